// Round 12
// baseline (246.435 us; speedup 1.0000x reference)
//
#include <hip/hip_runtime.h>

// ---------------------------------------------------------------------------
// MultiHeadAttention: x(4,2048,512) fp32, adj(4,2048,2048) 0/1 fp32
// R12: intra-block key-parity split. Waves 0,1 = even k-tiles, waves 2,3 =
// odd; each wave 64 q-rows (4 qg). K/V LDS frag reads amortize 2x (they are
// wave-invariant -- were read 4x). Additive merge via LDS epilogue (no max).
// Masks: direct global prefetch (L2 broadcast), M_lds deleted. K=32 PV kept.
// ---------------------------------------------------------------------------

typedef __attribute__((ext_vector_type(8))) short bf16x8;
typedef __attribute__((ext_vector_type(4))) float f32x4;
typedef __attribute__((ext_vector_type(4))) unsigned short ushort4v;
typedef __attribute__((ext_vector_type(4))) _Float16 f16x4;
typedef __attribute__((ext_vector_type(8))) _Float16 f16x8;
typedef __attribute__((ext_vector_type(2))) __fp16 h16x2;  // cvt_pkrtz return type

#if __has_builtin(__builtin_amdgcn_exp2f)
#define EXP2F(x) __builtin_amdgcn_exp2f(x)
#else
#define EXP2F(x) exp2f(x)
#endif

// 0.125 (1/sqrt(64)) * log2(e), folded into Q at the QKV-gemm epilogue
#define QSCALE 0.18033688011112042f

__device__ __forceinline__ unsigned short f2bf(float f) {
  unsigned int u = __float_as_uint(f);
  u += 0x7FFFu + ((u >> 16) & 1u);
  return (unsigned short)(u >> 16);
}
__device__ __forceinline__ unsigned short f2h(float f) {
  union { _Float16 h; unsigned short u; } cv;
  cv.h = (_Float16)f;
  return cv.u;
}

// sign-extend bit (pos) of w to 0 / 0xFFFFFFFF
__device__ __forceinline__ int sbit(unsigned w, int pos) {
  return ((int)(w << (31 - pos))) >> 31;  // compiler emits v_bfe_i32
}

// pack 8 floats -> f16x8 via 4 packed RTZ converts
__device__ __forceinline__ f16x8 pk8(const float* p) {
  union { struct { h16x2 a, b, c, d; } s; f16x8 v; } u;
  u.s.a = __builtin_amdgcn_cvt_pkrtz(p[0], p[1]);
  u.s.b = __builtin_amdgcn_cvt_pkrtz(p[2], p[3]);
  u.s.c = __builtin_amdgcn_cvt_pkrtz(p[4], p[5]);
  u.s.d = __builtin_amdgcn_cvt_pkrtz(p[6], p[7]);
  return u.v;
}

// PV matmul: K=32 f16
__device__ __forceinline__ f32x4 mfma_pv(f16x8 a, f16x8 b, f32x4 c) {
#if __has_builtin(__builtin_amdgcn_mfma_f32_16x16x32_f16)
  return __builtin_amdgcn_mfma_f32_16x16x32_f16(a, b, c, 0, 0, 0);
#else
  union { f16x8 v; struct { f16x4 lo, hi; } s; } ua, ub;
  ua.v = a; ub.v = b;
  c = __builtin_amdgcn_mfma_f32_16x16x16f16(ua.s.lo, ub.s.lo, c, 0, 0, 0);
  return __builtin_amdgcn_mfma_f32_16x16x16f16(ua.s.hi, ub.s.hi, c, 0, 0, 0);
#endif
}

// ---------------- fused prep: casts + adj bit-pack, one launch ---------------
__global__ __launch_bounds__(256) void prep_k(const float* __restrict__ x,
                                              unsigned short* __restrict__ x_bf,
                                              const float* __restrict__ wqkv,
                                              unsigned short* __restrict__ wqkv_bf,
                                              const float* __restrict__ outw,
                                              unsigned short* __restrict__ outw_bf,
                                              const float* __restrict__ adj,
                                              unsigned long long* __restrict__ abits) {
  const int bid = blockIdx.x;
  if (bid < 5120) {
    const float* in; unsigned short* out; int i;
    if (bid < 4096) { in = x; out = x_bf; i = bid * 256 + threadIdx.x; }
    else if (bid < 4864) { in = wqkv; out = wqkv_bf; i = (bid - 4096) * 256 + threadIdx.x; }
    else { in = outw; out = outw_bf; i = (bid - 4864) * 256 + threadIdx.x; }
    float4 v = ((const float4*)in)[i];
    ushort4v o;
    o[0] = f2bf(v.x); o[1] = f2bf(v.y); o[2] = f2bf(v.z); o[3] = f2bf(v.w);
    ((ushort4v*)out)[i] = o;
  } else {
    const int gw = (bid - 5120) * 4 + (threadIdx.x >> 6);  // 0..8191 = b*2048+q
    const int l = threadIdx.x & 63;
    const int b = gw >> 11, q = gw & 2047;
    const float* row = adj + ((size_t)b * 2048 + q) * 2048;
    unsigned long long* ob = abits + (size_t)b * 65536 + q;
#pragma unroll 4
    for (int kt = 0; kt < 32; ++kt) {
      const float v = row[kt * 64 + l];
      const unsigned long long m = __ballot(v != 0.f);
      if (l == 0) ob[(size_t)kt * 2048] = m;
    }
  }
}

// ---------------- 128x128 bf16 MFMA GEMM: C = A @ Bt^T (+bias) ----------------
template <int MODE>
__global__ __launch_bounds__(256, 3) void gemm128_k(const unsigned short* __restrict__ A,
                                                    const unsigned short* __restrict__ Bt,
                                                    const float* __restrict__ bias, int Kdim,
                                                    int Ntiles, unsigned short* __restrict__ q_out,
                                                    unsigned short* __restrict__ k_out,
                                                    unsigned short* __restrict__ v_out,
                                                    float* __restrict__ f_out) {
  __shared__ union {
    struct { unsigned short A[2][128][40], B[2][128][40]; } s;  // 40 KB
    unsigned short T[64][136];                                  // V-transpose staging
  } u;

  const int t = threadIdx.x;
  const int lane = t & 63, w = t >> 6, ln = lane & 15, quad = lane >> 4;
  const int xcd = blockIdx.x & 7, loc = blockIdx.x >> 3;
  const int mt = xcd * ((gridDim.x >> 3) / Ntiles) + loc / Ntiles;
  const int nt = loc % Ntiles;
  const int wm = (w >> 1) * 64, wn = (w & 1) * 64;
  const int strow = t >> 2, stcol = (t & 3) * 8;

  const size_t abase = (size_t)(mt * 128 + strow) * Kdim + stcol;
  const size_t bbase = (size_t)(nt * 128 + strow) * Kdim + stcol;

  f32x4 acc[4][4];
#pragma unroll
  for (int i = 0; i < 4; ++i)
#pragma unroll
    for (int j = 0; j < 4; ++j) acc[i][j] = (f32x4){0.f, 0.f, 0.f, 0.f};

  bf16x8 a0 = *(const bf16x8*)(A + abase);
  bf16x8 a1 = *(const bf16x8*)(A + abase + (size_t)64 * Kdim);
  bf16x8 b0 = *(const bf16x8*)(Bt + bbase);
  bf16x8 b1 = *(const bf16x8*)(Bt + bbase + (size_t)64 * Kdim);
  *(bf16x8*)&u.s.A[0][strow][stcol] = a0;
  *(bf16x8*)&u.s.A[0][64 + strow][stcol] = a1;
  *(bf16x8*)&u.s.B[0][strow][stcol] = b0;
  *(bf16x8*)&u.s.B[0][64 + strow][stcol] = b1;
  __syncthreads();

  const int iters = Kdim >> 5;
  for (int it = 0; it < iters; ++it) {
    const int cur = it & 1, nxt = cur ^ 1;

    const int kn = ((it + 1) << 5) & (Kdim - 1);
    a0 = *(const bf16x8*)(A + abase + kn);
    a1 = *(const bf16x8*)(A + abase + (size_t)64 * Kdim + kn);
    b0 = *(const bf16x8*)(Bt + bbase + kn);
    b1 = *(const bf16x8*)(Bt + bbase + (size_t)64 * Kdim + kn);

    bf16x8 bfr[4];
#pragma unroll
    for (int nf = 0; nf < 4; ++nf)
      bfr[nf] = *(const bf16x8*)&u.s.B[cur][wn + nf * 16 + ln][quad * 8];
#pragma unroll
    for (int mf = 0; mf < 4; ++mf) {
      bf16x8 af = *(const bf16x8*)&u.s.A[cur][wm + mf * 16 + ln][quad * 8];
#pragma unroll
      for (int nf = 0; nf < 4; ++nf)
        acc[mf][nf] = __builtin_amdgcn_mfma_f32_16x16x32_bf16(af, bfr[nf], acc[mf][nf], 0, 0, 0);
    }

    if (it + 1 < iters) {
      *(bf16x8*)&u.s.A[nxt][strow][stcol] = a0;
      *(bf16x8*)&u.s.A[nxt][64 + strow][stcol] = a1;
      *(bf16x8*)&u.s.B[nxt][strow][stcol] = b0;
      *(bf16x8*)&u.s.B[nxt][64 + strow][stcol] = b1;
      __syncthreads();
    }
  }

  if (MODE == 0 && nt >= 8) {
    const int bb = mt >> 4, sq0 = (mt & 15) * 128;
#pragma unroll
    for (int half = 0; half < 2; ++half) {
      __syncthreads();
      if ((w & 1) == half) {
#pragma unroll
        for (int nf = 0; nf < 4; ++nf) {
          const float bv = bias[nt * 128 + half * 64 + nf * 16 + ln];
#pragma unroll
          for (int mf = 0; mf < 4; ++mf)
#pragma unroll
            for (int r = 0; r < 4; ++r)
              u.T[nf * 16 + ln][wm + mf * 16 + quad * 4 + r] = f2h(acc[mf][nf][r] + bv);
        }
      }
      __syncthreads();
#pragma unroll
      for (int rep = 0; rep < 4; ++rep) {
        const int row = rep * 16 + (t >> 4), c = t & 15;
        const bf16x8 val = *(const bf16x8*)&u.T[row][c * 8];
        const int hd = (nt - 8) * 128 + half * 64 + row;
        const int hh = hd >> 6, dd = hd & 63;
        *(bf16x8*)(v_out + ((size_t)(bb * 8 + hh) * 64 + dd) * 2048 + sq0 + c * 8) = val;
      }
    }
    return;
  }

#pragma unroll
  for (int mf = 0; mf < 4; ++mf) {
    const int m = mt * 128 + wm + mf * 16 + quad * 4;
#pragma unroll
    for (int nf = 0; nf < 4; ++nf) {
      const int n = nt * 128 + wn + nf * 16 + ln;
      const float bv = bias[n];
      if (MODE == 0) {
        const int hd = n & 511;
        const int hh = hd >> 6, dd = hd & 63;
        const int bb = m >> 11, sq = m & 2047;
        if (n < 512) {
#pragma unroll
          for (int r = 0; r < 4; ++r)
            q_out[((size_t)(bb * 8 + hh) * 2048 + sq + r) * 64 + dd] =
                f2bf((acc[mf][nf][r] + bv) * QSCALE);
        } else {
#pragma unroll
          for (int r = 0; r < 4; ++r)
            k_out[((size_t)(bb * 8 + hh) * 2048 + sq + r) * 64 + dd] = f2bf(acc[mf][nf][r] + bv);
        }
      } else {
#pragma unroll
        for (int r = 0; r < 4; ++r) f_out[(size_t)(m + r) * 512 + n] = acc[mf][nf][r] + bv;
      }
    }
  }
}

// ---------------- fused flash attention, key-parity split, K=32 PV ----------
// grid 512: bh = blk&31, qt = blk>>5. 4 waves: pr=w>>1 (tile parity),
// half=w&1 (q 64-row half). Each wave: 64 q x its 16 tiles. Additive merge
// in LDS epilogue. Masks prefetched from global (no M_lds).
__global__ __launch_bounds__(256, 2) void attn_k(const unsigned short* __restrict__ Qg,
                                                 const unsigned short* __restrict__ Kg,
                                                 const unsigned short* __restrict__ Vg,
                                                 const unsigned long long* __restrict__ Mg,
                                                 unsigned short* __restrict__ Og) {
  __shared__ union {
    struct {
      unsigned short K[2][64][76];  // [buf][key][d] bf16 (76: permuted rows 2-way)
      unsigned short V[2][64][72];  // [buf][d][key] f16
    } st;
    struct {
      float O[2][64][68];  // [half][q_local][d] partials from waves 2,3
      float L[2][64];
    } mg;
  } u;

  const int t = threadIdx.x;
  const int w = t >> 6, lane = t & 63, ln = lane & 15, quad = lane >> 4;
  const int pr = w >> 1, half = w & 1;
  const int bh = blockIdx.x & 31, qt = blockIdx.x >> 5, bb = bh >> 3;
  const int sbase = qt * 128;

  const unsigned short* Qp = Qg + (size_t)bh * (2048 * 64);
  const unsigned short* Kp = Kg + (size_t)bh * (2048 * 64);
  const unsigned short* Vp = Vg + (size_t)bh * (64 * 2048);
  // lane's mask base: row q = sbase + half*64 + qg*16 + ln, index [kt*2048 + qg*16]
  const unsigned long long* Mq = Mg + (size_t)bb * 65536 + sbase + half * 64 + ln;

  // Q B-frags for 4 qg (64 q-rows per wave)
  bf16x8 qf[4][2];
#pragma unroll
  for (int qg = 0; qg < 4; ++qg) {
    const int qrow = sbase + half * 64 + qg * 16 + ln;
    qf[qg][0] = *(const bf16x8*)(Qp + (size_t)qrow * 64 + quad * 8);
    qf[qg][1] = *(const bf16x8*)(Qp + (size_t)qrow * 64 + 32 + quad * 8);
  }

  const _Float16 one_h = (_Float16)((ln == 0) ? 1.0f : 0.0f);
  const f16x8 vf_one = (f16x8){one_h, one_h, one_h, one_h, one_h, one_h, one_h, one_h};

  f32x4 acc_o[4][4];
#pragma unroll
  for (int qg = 0; qg < 4; ++qg)
#pragma unroll
    for (int dg = 0; dg < 4; ++dg) acc_o[qg][dg] = (f32x4){0.f, 0.f, 0.f, 0.f};
  f32x4 acc_1[4];
#pragma unroll
  for (int qg = 0; qg < 4; ++qg) acc_1[qg] = (f32x4){0.f, 0.f, 0.f, 0.f};

  const int strow = t >> 2;
  const int stcol = (t & 3) * 16;

  const unsigned short* Kl = Kp + (size_t)strow * 64 + stcol;
  const unsigned short* Vl = Vp + (size_t)strow * 2048 + stcol;

  // stage tile 0 into buf 0
  bf16x8 kr0 = *(const bf16x8*)(Kl);
  bf16x8 kr1 = *(const bf16x8*)(Kl + 8);
  bf16x8 vr0 = *(const bf16x8*)(Vl);
  bf16x8 vr1 = *(const bf16x8*)(Vl + 8);
  *(bf16x8*)&u.st.K[0][strow][stcol] = kr0;
  *(bf16x8*)&u.st.K[0][strow][stcol + 8] = kr1;
  *(bf16x8*)&u.st.V[0][strow][stcol] = vr0;
  *(bf16x8*)&u.st.V[0][strow][stcol + 8] = vr1;

  // prefetch masks for first active tile (kt = pr)
  unsigned long long mk[4];
#pragma unroll
  for (int qg = 0; qg < 4; ++qg) mk[qg] = Mq[(size_t)pr * 2048 + qg * 16];
  __syncthreads();

  const int kperm = ((ln >> 2) << 3) + (ln & 3);  // permuted K row base

  for (int kt = 0; kt < 32; ++kt) {
    const int cur = kt & 1, nxt = cur ^ 1;

    // prefetch K/V for kt+1 (all waves; drained at staging below)
    kr0 = *(const bf16x8*)(Kl + (size_t)(kt + 1) * 4096);
    kr1 = *(const bf16x8*)(Kl + (size_t)(kt + 1) * 4096 + 8);
    vr0 = *(const bf16x8*)(Vl + (kt + 1) * 64);
    vr1 = *(const bf16x8*)(Vl + (kt + 1) * 64 + 8);

    if ((kt & 1) == pr) {
      // prefetch masks for next active tile (kt+2)
      unsigned long long mkn[4];
#pragma unroll
      for (int qg = 0; qg < 4; ++qg) mkn[qg] = Mq[(size_t)(kt + 2) * 2048 + qg * 16];

#pragma unroll
      for (int h = 0; h < 2; ++h) {
        // S^T for keys h*32..h*32+31 (permuted rows), 4 qg
        f32x4 sc[4][2];
#pragma unroll
        for (int e = 0; e < 2; ++e) {
          const int krow = h * 32 + kperm + e * 4;
          bf16x8 kf0 = *(const bf16x8*)&u.st.K[cur][krow][quad * 8];
          bf16x8 kf1 = *(const bf16x8*)&u.st.K[cur][krow][32 + quad * 8];
#pragma unroll
          for (int qg = 0; qg < 4; ++qg) {
            f32x4 z = (f32x4){0.f, 0.f, 0.f, 0.f};
            z = __builtin_amdgcn_mfma_f32_16x16x32_bf16(kf0, qf[qg][0], z, 0, 0, 0);
            sc[qg][e] = __builtin_amdgcn_mfma_f32_16x16x32_bf16(kf1, qf[qg][1], z, 0, 0, 0);
          }
        }

        // V-frags (b128)
        f16x8 vfa[4];
#pragma unroll
        for (int dg = 0; dg < 4; ++dg)
          vfa[dg] = *(const f16x8*)&u.st.V[cur][dg * 16 + ln][h * 32 + quad * 8];

        // mask + exp2 -> P (K=32 A-slot order), then PV
#pragma unroll
        for (int qg = 0; qg < 4; ++qg) {
          const unsigned wrd =
              (h ? (unsigned)(mk[qg] >> 32) : (unsigned)mk[qg]) >> (quad * 8);
          float p[8];
#pragma unroll
          for (int e = 0; e < 2; ++e)
#pragma unroll
            for (int r = 0; r < 4; ++r) {
              const int j = e * 4 + r;
              const int se = sbit(wrd, j);
              const float s = __int_as_float(__float_as_int(sc[qg][e][r]) & se);
              p[j] = EXP2F(s);
            }
          const f16x8 pa = pk8(p);
#pragma unroll
          for (int dg = 0; dg < 4; ++dg)
            acc_o[qg][dg] = mfma_pv(pa, vfa[dg], acc_o[qg][dg]);
          acc_1[qg] = mfma_pv(pa, vf_one, acc_1[qg]);
        }
      }
#pragma unroll
      for (int qg = 0; qg < 4; ++qg) mk[qg] = mkn[qg];
    }

    if (kt < 31) {
      *(bf16x8*)&u.st.K[nxt][strow][stcol] = kr0;
      *(bf16x8*)&u.st.K[nxt][strow][stcol + 8] = kr1;
      *(bf16x8*)&u.st.V[nxt][strow][stcol] = vr0;
      *(bf16x8*)&u.st.V[nxt][strow][stcol + 8] = vr1;
      __syncthreads();
    }
  }

  // ---------------- merge epilogue: waves 2,3 -> LDS; waves 0,1 combine -------
  __syncthreads();  // staging buffers dead; mg aliases them
  if (pr == 1) {
#pragma unroll
    for (int qg = 0; qg < 4; ++qg) {
#pragma unroll
      for (int r = 0; r < 4; ++r) {
        const int ql = qg * 16 + quad * 4 + r;
#pragma unroll
        for (int dg = 0; dg < 4; ++dg) u.mg.O[half][ql][dg * 16 + ln] = acc_o[qg][dg][r];
      }
      if (ln == 0)
#pragma unroll
        for (int r = 0; r < 4; ++r) u.mg.L[half][qg * 16 + quad * 4 + r] = acc_1[qg][r];
    }
  }
  __syncthreads();
  if (pr == 0) {
    unsigned short* Op = Og + (size_t)bb * 2048 * 512 + (size_t)(bh & 7) * 64;
#pragma unroll
    for (int qg = 0; qg < 4; ++qg)
#pragma unroll
      for (int r = 0; r < 4; ++r) {
        const int ql = qg * 16 + quad * 4 + r;
        const float lsum = __shfl(acc_1[qg][r], quad * 16) + u.mg.L[half][ql];
        const float inv = 1.0f / lsum;
        const int sq = sbase + half * 64 + ql;
#pragma unroll
        for (int dg = 0; dg < 4; ++dg)
          Op[(size_t)sq * 512 + dg * 16 + ln] =
              f2bf((acc_o[qg][dg][r] + u.mg.O[half][ql][dg * 16 + ln]) * inv);
      }
  }
}

// ---------------------------------------------------------------------------
extern "C" void kernel_launch(void* const* d_in, const int* in_sizes, int n_in, void* d_out,
                              int out_size, void* d_ws, size_t ws_size, hipStream_t stream) {
  const float* x = (const float*)d_in[0];
  const float* adj = (const float*)d_in[1];
  const float* wqkv = (const float*)d_in[2];
  const float* bqkv = (const float*)d_in[3];
  const float* outw = (const float*)d_in[4];
  const float* outb = (const float*)d_in[5];
  float* out = (float*)d_out;

  char* ws = (char*)d_ws;
  unsigned short* x_bf = (unsigned short*)(ws);                      //  8.0 MB
  unsigned short* wqkv_bf = (unsigned short*)(ws + 8388608);         //  1.5 MB
  unsigned short* outw_bf = (unsigned short*)(ws + 9961472);         //  0.5 MB
  unsigned long long* abits = (unsigned long long*)(ws + 10485760);  //  2.0 MB
  unsigned short* Qb = (unsigned short*)(ws + 27262976);             //  8.0 MB (b,h,s,d) bf16
  unsigned short* Kb = (unsigned short*)(ws + 35651584);             //  8.0 MB (b,h,s,d) bf16
  unsigned short* Vb = (unsigned short*)(ws + 44040192);             //  8.0 MB (b,h,d,s) f16
  unsigned short* Ob = (unsigned short*)(ws + 52428800);             //  8.0 MB (b,s,e) bf16

  prep_k<<<7168, 256, 0, stream>>>(x, x_bf, wqkv, wqkv_bf, outw, outw_bf, adj, abits);

  gemm128_k<0><<<768, 256, 0, stream>>>(x_bf, wqkv_bf, bqkv, 512, 12, Qb, Kb, Vb, nullptr);

  attn_k<<<512, 256, 0, stream>>>(Qb, Kb, Vb, abits, Ob);

  gemm128_k<1><<<256, 256, 0, stream>>>(Ob, outw_bf, outb, 512, 4, nullptr, nullptr, nullptr, out);
}